// Round 4
// baseline (397.063 us; speedup 1.0000x reference)
//
#include <hip/hip_runtime.h>
#include <stdint.h>

// Problem constants
#define NB   64          // batches
#define NS   64          // sensors
#define NT   2030        // time samples
#define NP   16384       // ROI*ROI pixels
#define DAS_ELEMS (NB * NP)          // 1,048,576

typedef float v4f __attribute__((ext_vector_type(4)));

// ---------------------------------------------------------------------------
// Kernel 0: transpose geometry (pixel,s) -> (s,pixel), fusing clamp + valid.
//   tc[s*NP + p] = (u16)clamp(t_idx[p*NS + s], 0, NT-1)   (NT < 65536)
//   wv[s*NP + p] = (0 <= t < NT) ? weights[p*NS + s] : 0
// ---------------------------------------------------------------------------
__global__ __launch_bounds__(256) void prep_kernel(
    const int* __restrict__ t_idx, const float* __restrict__ w,
    unsigned short* __restrict__ tc, float* __restrict__ wv)
{
    __shared__ int   ti[64][65];
    __shared__ float wf[64][65];
    const int pbase = blockIdx.x * 64;

    #pragma unroll
    for (int k = 0; k < 16; ++k) {
        int o = k * 256 + threadIdx.x;     // 0..4095
        int r = o >> 6, s = o & 63;        // r = pixel-in-tile, s = sensor
        ti[r][s] = t_idx[pbase * 64 + o];
        wf[r][s] = w[pbase * 64 + o];
    }
    __syncthreads();

    #pragma unroll
    for (int k = 0; k < 16; ++k) {
        int o = k * 256 + threadIdx.x;
        int s = o >> 6, r = o & 63;
        int t = ti[r][s];
        bool valid = (t >= 0) & (t < NT);
        int tcl = min(max(t, 0), NT - 1);
        tc[s * NP + pbase + r] = (unsigned short)tcl;
        wv[s * NP + pbase + r] = valid ? wf[r][s] : 0.0f;
    }
}

// ---------------------------------------------------------------------------
// Kernel 1 (fast path): XCD-confined sinogram, full occupancy.
//
// grid 2048 linear blocks x 256 threads; 1 pixel/thread, 2 batches/block.
// Swizzle: xcd = bid&7 (HW round-robins consecutive blocks across the 8
// XCDs), and we give XCD k ONLY batch-pairs {4k..4k+3} (8 batches). Its
// sinogram slice = 8 x 64 rows x 8KB = 4.1 MB, and since all its blocks
// sweep s in lockstep-ish order the LIVE window is ~1 MB -> gathers hit the
// per-XCD L2 (~200cy, 34 TB/s agg) instead of streaming from Infinity Cache
// (~600cy) as with the default all-XCDs-see-all-batches mapping.
// 8 blocks/CU (32 waves) doubles latency hiding vs rounds 0-3 (4 blocks):
// each wave serially stalls on its gather vmcnt every sensor iteration, so
// resident-wave count is the only thing covering that stall.
// Geometry t/w loads are NONTEMPORAL: they are a read-once 24 MB/XCD stream
// per sweep and must not evict the L2-resident sinogram. pix stores stay
// nontemporal (never re-read). Lane-to-lane delta-t ~5.3 samples = 21 B ->
// ~3 lanes share a gather line (best known mapping, kept from round 3).
// ---------------------------------------------------------------------------
__global__ __launch_bounds__(256) void main_l2_kernel(
    const float* __restrict__ sino,          // (B, S, T)
    const unsigned short* __restrict__ tptr, // (S, NP) clamped u16
    const float* __restrict__ wptr,          // (S, NP) masked
    float*       __restrict__ das,           // (B, NP) raw relu'd
    float*       __restrict__ pix,           // (B, S, NP)
    unsigned*    __restrict__ bmax)          // per-batch max (float bits)
{
    const int tid  = threadIdx.x;
    const int bid  = blockIdx.x;         // 0..2047
    const int xcd  = bid & 7;            // HW XCD for this block (heuristic)
    const int j    = bid >> 3;           // 0..255 within XCD
    const int tile = j & 63;             // 0..63 pixel tile
    const int pair = xcd * 4 + (j >> 6); // 0..31 batch pair, confined per XCD
    const int b0   = pair * 2, b1 = b0 + 1;
    const int p    = tile * 256 + tid;   // this thread's pixel

    const float* __restrict__ sr0 = sino + (size_t)b0 * (NS * NT);
    const float* __restrict__ sr1 = sino + (size_t)b1 * (NS * NT);
    float* __restrict__ pix0 = pix + ((size_t)b0 * NS) * NP + p;
    float* __restrict__ pix1 = pix + ((size_t)b1 * NS) * NP + p;

    float a0 = 0.f, a1 = 0.f;

    // prefetch t/w for s = 0 (nontemporal: read-once stream, keep out of L2)
    int   t = __builtin_nontemporal_load(tptr + p);
    float w = __builtin_nontemporal_load(wptr + p);

    for (int s = 0; s < NS; ++s) {
        // distance-1 register prefetch of next sensor's t/w
        int nt = 0; float nw = 0.f;
        if (s + 1 < NS) {
            nt = __builtin_nontemporal_load(tptr + (s + 1) * NP + p);
            nw = __builtin_nontemporal_load(wptr + (s + 1) * NP + p);
        }

        const float* __restrict__ r0 = sr0 + s * NT;
        const float* __restrict__ r1 = sr1 + s * NT;
        float v0 = r0[t] * w;
        float v1 = r1[t] * w;

        __builtin_nontemporal_store(v0, pix0 + (size_t)s * NP);
        __builtin_nontemporal_store(v1, pix1 + (size_t)s * NP);

        a0 += v0; a1 += v1;
        t = nt; w = nw;
    }

    // relu
    a0 = fmaxf(a0, 0.f);
    a1 = fmaxf(a1, 0.f);
    das[(size_t)b0 * NP + p] = a0;
    das[(size_t)b1 * NP + p] = a1;

    // per-batch block max -> atomic max
    float m0 = a0, m1 = a1;
    #pragma unroll
    for (int off = 32; off > 0; off >>= 1) {
        m0 = fmaxf(m0, __shfl_down(m0, off, 64));
        m1 = fmaxf(m1, __shfl_down(m1, off, 64));
    }
    __shared__ float wm0[4], wm1[4];
    const int wid = tid >> 6, lane = tid & 63;
    if (lane == 0) { wm0[wid] = m0; wm1[wid] = m1; }
    __syncthreads();
    if (tid == 0) {
        m0 = fmaxf(fmaxf(wm0[0], wm0[1]), fmaxf(wm0[2], wm0[3]));
        m1 = fmaxf(fmaxf(wm1[0], wm1[1]), fmaxf(wm1[2], wm1[3]));
        atomicMax(&bmax[b0], __float_as_uint(m0));  // vals >= 0: uint order == float order
        atomicMax(&bmax[b1], __float_as_uint(m1));
    }
}

// ---------------------------------------------------------------------------
// Kernel 1 (fallback, ws too small): original non-transposed path.
// ---------------------------------------------------------------------------
__global__ __launch_bounds__(256) void main_fallback_kernel(
    const float* __restrict__ sino,
    const int*   __restrict__ tptr,
    const float* __restrict__ wptr,
    float*       __restrict__ das,
    float*       __restrict__ pix,
    unsigned*    __restrict__ bmax)
{
    const int b = blockIdx.y;
    const int p = blockIdx.x * 1024 + threadIdx.x * 4;
    const float* __restrict__ srow = sino + (size_t)b * (NS * NT);
    float* __restrict__ pixb = pix + (size_t)b * ((size_t)NS * NP) + p;

    v4f acc = (v4f)(0.0f);

    for (int s = 0; s < NS; ++s) {
        int t0 = tptr[(p + 0) * NS + s];
        int t1 = tptr[(p + 1) * NS + s];
        int t2 = tptr[(p + 2) * NS + s];
        int t3 = tptr[(p + 3) * NS + s];
        float wx = ((t0 >= 0) & (t0 < NT)) ? wptr[(p + 0) * NS + s] : 0.f;
        float wy = ((t1 >= 0) & (t1 < NT)) ? wptr[(p + 1) * NS + s] : 0.f;
        float wz = ((t2 >= 0) & (t2 < NT)) ? wptr[(p + 2) * NS + s] : 0.f;
        float ww = ((t3 >= 0) & (t3 < NT)) ? wptr[(p + 3) * NS + s] : 0.f;
        int4 t;
        t.x = min(max(t0, 0), NT - 1);
        t.y = min(max(t1, 0), NT - 1);
        t.z = min(max(t2, 0), NT - 1);
        t.w = min(max(t3, 0), NT - 1);
        const float* __restrict__ sr = srow + s * NT;
        v4f v;
        v.x = sr[t.x] * wx;
        v.y = sr[t.y] * wy;
        v.z = sr[t.z] * wz;
        v.w = sr[t.w] * ww;
        __builtin_nontemporal_store(v, (v4f*)(pixb + (size_t)s * NP));
        acc += v;
    }

    acc.x = fmaxf(acc.x, 0.f); acc.y = fmaxf(acc.y, 0.f);
    acc.z = fmaxf(acc.z, 0.f); acc.w = fmaxf(acc.w, 0.f);
    *(v4f*)(das + (size_t)b * NP + p) = acc;

    float m = fmaxf(fmaxf(acc.x, acc.y), fmaxf(acc.z, acc.w));
    #pragma unroll
    for (int off = 32; off > 0; off >>= 1)
        m = fmaxf(m, __shfl_down(m, off, 64));
    __shared__ float wm[4];
    if ((threadIdx.x & 63) == 0) wm[threadIdx.x >> 6] = m;
    __syncthreads();
    if (threadIdx.x == 0) {
        m = fmaxf(fmaxf(wm[0], wm[1]), fmaxf(wm[2], wm[3]));
        atomicMax(&bmax[b], __float_as_uint(m));
    }
}

// ---------------------------------------------------------------------------
// Kernel 2: normalize das in place. 1M elems / 4 per thread.
// ---------------------------------------------------------------------------
__global__ __launch_bounds__(256) void norm_kernel(
    float* __restrict__ das, const unsigned* __restrict__ bmax)
{
    int idx = (blockIdx.x * 256 + threadIdx.x) * 4;
    int b = idx >> 14;                   // NP = 16384 pixels per batch
    float m = __uint_as_float(bmax[b]);
    m = (m > 1e-8f) ? m : 1.0f;
    v4f v = *(v4f*)(das + idx);
    v.x = v.x / m; v.y = v.y / m; v.z = v.z / m; v.w = v.w / m;
    *(v4f*)(das + idx) = v;
}

extern "C" void kernel_launch(void* const* d_in, const int* in_sizes, int n_in,
                              void* d_out, int out_size, void* d_ws, size_t ws_size,
                              hipStream_t stream)
{
    const float* sino  = (const float*)d_in[0];   // (64,1,64,2030) f32
    const float* w     = (const float*)d_in[1];   // (128,128,64)   f32
    const int*   t_idx = (const int*)  d_in[2];   // (128,128,64)   i32
    // d_in[3] (valid_mask) intentionally unused: valid == (0 <= t_idx < NT)

    float* das = (float*)d_out;                   // first 1,048,576 floats
    float* pix = (float*)d_out + DAS_ELEMS;       // next 67,108,864 floats

    char* ws = (char*)d_ws;
    // layout: wv f32 (4 MB) | tc u16 (2 MB) | bmax (256 B)
    const size_t need = (size_t)(6u << 20) + 256;
    const bool big = ws_size >= need;

    unsigned* bmax;
    float* wv = nullptr; unsigned short* tc = nullptr;
    if (big) {
        wv   = (float*)ws;                            // 4 MB
        tc   = (unsigned short*)(ws + (4u << 20));    // 2 MB
        bmax = (unsigned*)(ws + (6u << 20));          // 256 B
    } else {
        bmax = (unsigned*)ws;                         // need only 256 B
    }

    (void)hipMemsetAsync(bmax, 0, NB * sizeof(unsigned), stream);

    if (big) {
        prep_kernel<<<256, 256, 0, stream>>>(t_idx, w, tc, wv);
        main_l2_kernel<<<2048, 256, 0, stream>>>(sino, tc, wv, das, pix, bmax);
    } else {
        main_fallback_kernel<<<dim3(16, NB), 256, 0, stream>>>(sino, t_idx, w, das, pix, bmax);
    }
    norm_kernel<<<DAS_ELEMS / 1024, 256, 0, stream>>>(das, bmax);
}

// Round 5
// 360.904 us; speedup vs baseline: 1.1002x; 1.1002x over previous
//
#include <hip/hip_runtime.h>
#include <stdint.h>

// Problem constants
#define NB   64          // batches
#define NS   64          // sensors
#define NT   2030        // time samples
#define NP   16384       // ROI*ROI pixels
#define DAS_ELEMS (NB * NP)          // 1,048,576

typedef float v4f __attribute__((ext_vector_type(4)));

// ---------------------------------------------------------------------------
// Kernel 0: transpose geometry (pixel,s) -> (s,pixel), fusing clamp + valid.
//   tc[s*NP + p] = (u16)clamp(t_idx[p*NS + s], 0, NT-1)   (NT < 65536)
//   wv[s*NP + p] = (0 <= t < NT) ? weights[p*NS + s] : 0
// ---------------------------------------------------------------------------
__global__ __launch_bounds__(256) void prep_kernel(
    const int* __restrict__ t_idx, const float* __restrict__ w,
    unsigned short* __restrict__ tc, float* __restrict__ wv)
{
    __shared__ int   ti[64][65];
    __shared__ float wf[64][65];
    const int pbase = blockIdx.x * 64;

    #pragma unroll
    for (int k = 0; k < 16; ++k) {
        int o = k * 256 + threadIdx.x;     // 0..4095
        int r = o >> 6, s = o & 63;        // r = pixel-in-tile, s = sensor
        ti[r][s] = t_idx[pbase * 64 + o];
        wf[r][s] = w[pbase * 64 + o];
    }
    __syncthreads();

    #pragma unroll
    for (int k = 0; k < 16; ++k) {
        int o = k * 256 + threadIdx.x;
        int s = o >> 6, r = o & 63;
        int t = ti[r][s];
        bool valid = (t >= 0) & (t < NT);
        int tcl = min(max(t, 0), NT - 1);
        tc[s * NP + pbase + r] = (unsigned short)tcl;
        wv[s * NP + pbase + r] = valid ? wf[r][s] : 0.0f;
    }
}

// ---------------------------------------------------------------------------
// Kernel 1 (fast path): batch-quad + sensor-unroll-2 = 8 gathers in flight.
//
// grid 1024 linear blocks x 256 threads; 1 pixel/thread, 4 batches/block,
// 2 sensors per loop iteration.
//
// Latency theory (rounds 0-4 evidence): instruction counts, traffic and
// occupancy each varied 2-4x across rounds with <8% total effect; the only
// variable correlating with the ranking is OUTSTANDING GATHERS PER WAVE
// (R3: 4 -> 367us best; R4: 2 -> 397us worst). So the loop is bound by the
// per-iteration vmcnt wait on gather results, not by any throughput term.
// This kernel: 8 independent gathers (4 batches x 2 sensors) are issued
// before the first consume, and t/w for s+2/s+3 are prefetched a full
// iteration ahead (cached loads -- R4's nontemporal t/w forced 32x re-reads
// to L3 and is reverted).
//
// XCD confinement: bid&7 is the HW XCD (round-robin dispatch); quad =
// (bid&7)*2 + (bid>>9) gives each XCD only 2 batch-quads = 8 batches.
// Its sinogram slice is 4.2 MB and the live per-sensor window ~200 KB ->
// gathers hit the per-XCD L2 (~200cy) instead of Infinity Cache (~600cy),
// halving the latency to hide. Lane-to-lane delta-t ~5.3 samples = 21 B ->
// ~3-6 lanes share each gather line (kept from round 3).
// ---------------------------------------------------------------------------
__global__ __launch_bounds__(256) void main_quad_kernel(
    const float* __restrict__ sino,          // (B, S, T)
    const unsigned short* __restrict__ tptr, // (S, NP) clamped u16
    const float* __restrict__ wptr,          // (S, NP) masked
    float*       __restrict__ das,           // (B, NP) raw relu'd
    float*       __restrict__ pix,           // (B, S, NP)
    unsigned*    __restrict__ bmax)          // per-batch max (float bits)
{
    const int tid  = threadIdx.x;
    const int bid  = blockIdx.x;             // 0..1023
    const int xcd  = bid & 7;                // HW XCD (dispatch round-robin)
    const int r    = bid >> 3;               // 0..127
    const int quad = xcd * 2 + (r >> 6);     // 0..15; 2 quads per XCD
    const int tile = r & 63;                 // 0..63
    const int p    = tile * 256 + tid;       // this thread's pixel
    const int b0   = quad * 4;

    const float* __restrict__ sr0 = sino + (size_t)(b0 + 0) * (NS * NT);
    const float* __restrict__ sr1 = sino + (size_t)(b0 + 1) * (NS * NT);
    const float* __restrict__ sr2 = sino + (size_t)(b0 + 2) * (NS * NT);
    const float* __restrict__ sr3 = sino + (size_t)(b0 + 3) * (NS * NT);
    float* __restrict__ px0 = pix + ((size_t)(b0 + 0) * NS) * NP + p;
    float* __restrict__ px1 = pix + ((size_t)(b0 + 1) * NS) * NP + p;
    float* __restrict__ px2 = pix + ((size_t)(b0 + 2) * NS) * NP + p;
    float* __restrict__ px3 = pix + ((size_t)(b0 + 3) * NS) * NP + p;

    float a0 = 0.f, a1 = 0.f, a2 = 0.f, a3 = 0.f;

    // t/w for sensors s=0,1 (cached loads: shared by 16 blocks via L2/L3)
    int   tA = tptr[p];      float wA = wptr[p];
    int   tB = tptr[NP + p]; float wB = wptr[NP + p];

    for (int s = 0; s < NS; s += 2) {
        // distance-2 prefetch: t/w for s+2, s+3
        int ntA = 0, ntB = 0; float nwA = 0.f, nwB = 0.f;
        if (s + 2 < NS) {
            ntA = tptr[(s + 2) * NP + p]; nwA = wptr[(s + 2) * NP + p];
            ntB = tptr[(s + 3) * NP + p]; nwB = wptr[(s + 3) * NP + p];
        }

        // issue all 8 independent gathers before any consume
        const int oA = s * NT + tA;
        const int oB = (s + 1) * NT + tB;
        float g0a = sr0[oA], g1a = sr1[oA], g2a = sr2[oA], g3a = sr3[oA];
        float g0b = sr0[oB], g1b = sr1[oB], g2b = sr2[oB], g3b = sr3[oB];

        float v0a = g0a * wA, v1a = g1a * wA, v2a = g2a * wA, v3a = g3a * wA;
        float v0b = g0b * wB, v1b = g1b * wB, v2b = g2b * wB, v3b = g3b * wB;

        size_t qa = (size_t)s * NP, qb = (size_t)(s + 1) * NP;
        __builtin_nontemporal_store(v0a, px0 + qa);
        __builtin_nontemporal_store(v1a, px1 + qa);
        __builtin_nontemporal_store(v2a, px2 + qa);
        __builtin_nontemporal_store(v3a, px3 + qa);
        __builtin_nontemporal_store(v0b, px0 + qb);
        __builtin_nontemporal_store(v1b, px1 + qb);
        __builtin_nontemporal_store(v2b, px2 + qb);
        __builtin_nontemporal_store(v3b, px3 + qb);

        a0 += v0a + v0b;
        a1 += v1a + v1b;
        a2 += v2a + v2b;
        a3 += v3a + v3b;

        tA = ntA; wA = nwA; tB = ntB; wB = nwB;
    }

    // relu
    a0 = fmaxf(a0, 0.f); a1 = fmaxf(a1, 0.f);
    a2 = fmaxf(a2, 0.f); a3 = fmaxf(a3, 0.f);
    das[(size_t)(b0 + 0) * NP + p] = a0;
    das[(size_t)(b0 + 1) * NP + p] = a1;
    das[(size_t)(b0 + 2) * NP + p] = a2;
    das[(size_t)(b0 + 3) * NP + p] = a3;

    // per-batch block max -> atomic max
    float m0 = a0, m1 = a1, m2 = a2, m3 = a3;
    #pragma unroll
    for (int off = 32; off > 0; off >>= 1) {
        m0 = fmaxf(m0, __shfl_down(m0, off, 64));
        m1 = fmaxf(m1, __shfl_down(m1, off, 64));
        m2 = fmaxf(m2, __shfl_down(m2, off, 64));
        m3 = fmaxf(m3, __shfl_down(m3, off, 64));
    }
    __shared__ float wm[4][4];
    const int wid = tid >> 6, lane = tid & 63;
    if (lane == 0) { wm[wid][0] = m0; wm[wid][1] = m1; wm[wid][2] = m2; wm[wid][3] = m3; }
    __syncthreads();
    if (tid < 4) {  // thread k reduces batch b0+k
        float m = fmaxf(fmaxf(wm[0][tid], wm[1][tid]),
                        fmaxf(wm[2][tid], wm[3][tid]));
        atomicMax(&bmax[b0 + tid], __float_as_uint(m));  // vals >= 0: uint order == float order
    }
}

// ---------------------------------------------------------------------------
// Kernel 1 (fallback, ws too small): original non-transposed path.
// ---------------------------------------------------------------------------
__global__ __launch_bounds__(256) void main_fallback_kernel(
    const float* __restrict__ sino,
    const int*   __restrict__ tptr,
    const float* __restrict__ wptr,
    float*       __restrict__ das,
    float*       __restrict__ pix,
    unsigned*    __restrict__ bmax)
{
    const int b = blockIdx.y;
    const int p = blockIdx.x * 1024 + threadIdx.x * 4;
    const float* __restrict__ srow = sino + (size_t)b * (NS * NT);
    float* __restrict__ pixb = pix + (size_t)b * ((size_t)NS * NP) + p;

    v4f acc = (v4f)(0.0f);

    for (int s = 0; s < NS; ++s) {
        int t0 = tptr[(p + 0) * NS + s];
        int t1 = tptr[(p + 1) * NS + s];
        int t2 = tptr[(p + 2) * NS + s];
        int t3 = tptr[(p + 3) * NS + s];
        float wx = ((t0 >= 0) & (t0 < NT)) ? wptr[(p + 0) * NS + s] : 0.f;
        float wy = ((t1 >= 0) & (t1 < NT)) ? wptr[(p + 1) * NS + s] : 0.f;
        float wz = ((t2 >= 0) & (t2 < NT)) ? wptr[(p + 2) * NS + s] : 0.f;
        float ww = ((t3 >= 0) & (t3 < NT)) ? wptr[(p + 3) * NS + s] : 0.f;
        int4 t;
        t.x = min(max(t0, 0), NT - 1);
        t.y = min(max(t1, 0), NT - 1);
        t.z = min(max(t2, 0), NT - 1);
        t.w = min(max(t3, 0), NT - 1);
        const float* __restrict__ sr = srow + s * NT;
        v4f v;
        v.x = sr[t.x] * wx;
        v.y = sr[t.y] * wy;
        v.z = sr[t.z] * wz;
        v.w = sr[t.w] * ww;
        __builtin_nontemporal_store(v, (v4f*)(pixb + (size_t)s * NP));
        acc += v;
    }

    acc.x = fmaxf(acc.x, 0.f); acc.y = fmaxf(acc.y, 0.f);
    acc.z = fmaxf(acc.z, 0.f); acc.w = fmaxf(acc.w, 0.f);
    *(v4f*)(das + (size_t)b * NP + p) = acc;

    float m = fmaxf(fmaxf(acc.x, acc.y), fmaxf(acc.z, acc.w));
    #pragma unroll
    for (int off = 32; off > 0; off >>= 1)
        m = fmaxf(m, __shfl_down(m, off, 64));
    __shared__ float wm[4];
    if ((threadIdx.x & 63) == 0) wm[threadIdx.x >> 6] = m;
    __syncthreads();
    if (threadIdx.x == 0) {
        m = fmaxf(fmaxf(wm[0], wm[1]), fmaxf(wm[2], wm[3]));
        atomicMax(&bmax[b], __float_as_uint(m));
    }
}

// ---------------------------------------------------------------------------
// Kernel 2: normalize das in place. 1M elems / 4 per thread.
// ---------------------------------------------------------------------------
__global__ __launch_bounds__(256) void norm_kernel(
    float* __restrict__ das, const unsigned* __restrict__ bmax)
{
    int idx = (blockIdx.x * 256 + threadIdx.x) * 4;
    int b = idx >> 14;                   // NP = 16384 pixels per batch
    float m = __uint_as_float(bmax[b]);
    m = (m > 1e-8f) ? m : 1.0f;
    v4f v = *(v4f*)(das + idx);
    v.x = v.x / m; v.y = v.y / m; v.z = v.z / m; v.w = v.w / m;
    *(v4f*)(das + idx) = v;
}

extern "C" void kernel_launch(void* const* d_in, const int* in_sizes, int n_in,
                              void* d_out, int out_size, void* d_ws, size_t ws_size,
                              hipStream_t stream)
{
    const float* sino  = (const float*)d_in[0];   // (64,1,64,2030) f32
    const float* w     = (const float*)d_in[1];   // (128,128,64)   f32
    const int*   t_idx = (const int*)  d_in[2];   // (128,128,64)   i32
    // d_in[3] (valid_mask) intentionally unused: valid == (0 <= t_idx < NT)

    float* das = (float*)d_out;                   // first 1,048,576 floats
    float* pix = (float*)d_out + DAS_ELEMS;       // next 67,108,864 floats

    char* ws = (char*)d_ws;
    // layout: wv f32 (4 MB) | tc u16 (2 MB) | bmax (256 B)
    const size_t need = (size_t)(6u << 20) + 256;
    const bool big = ws_size >= need;

    unsigned* bmax;
    float* wv = nullptr; unsigned short* tc = nullptr;
    if (big) {
        wv   = (float*)ws;                            // 4 MB
        tc   = (unsigned short*)(ws + (4u << 20));    // 2 MB
        bmax = (unsigned*)(ws + (6u << 20));          // 256 B
    } else {
        bmax = (unsigned*)ws;                         // need only 256 B
    }

    (void)hipMemsetAsync(bmax, 0, NB * sizeof(unsigned), stream);

    if (big) {
        prep_kernel<<<256, 256, 0, stream>>>(t_idx, w, tc, wv);
        main_quad_kernel<<<1024, 256, 0, stream>>>(sino, tc, wv, das, pix, bmax);
    } else {
        main_fallback_kernel<<<dim3(16, NB), 256, 0, stream>>>(sino, t_idx, w, das, pix, bmax);
    }
    norm_kernel<<<DAS_ELEMS / 1024, 256, 0, stream>>>(das, bmax);
}